// Round 2
// baseline (584.156 us; speedup 1.0000x reference)
//
#include <hip/hip_runtime.h>
#include <hip/hip_bf16.h>

// Problem constants (from reference)
#define NV 4096
#define NE 8192
#define AD 64      // ATOM_DIM
#define BD 32      // BOND_DIM_P1
#define HD 128     // H
#define NL 4       // N_LAYER

typedef __hip_bfloat16 bf16;

__device__ __forceinline__ float leaky(float x) { return x > 0.f ? x : 0.01f * x; }

// dtype-generic load/store
template<typename T> __device__ __forceinline__ float ldf(const T* p, long i);
template<> __device__ __forceinline__ float ldf<float>(const float* p, long i) { return p[i]; }
template<> __device__ __forceinline__ float ldf<bf16>(const bf16* p, long i) { return __bfloat162float(p[i]); }

template<typename T> __device__ __forceinline__ void stf(T* p, long i, float v);
template<> __device__ __forceinline__ void stf<float>(float* p, long i, float v) { p[i] = v; }
template<> __device__ __forceinline__ void stf<bf16>(bf16* p, long i, float v) { p[i] = __float2bfloat16(v); }

__device__ __forceinline__ int clampv(int x) { return min(max(x, 0), NV - 1); }

// he lives in its final output slot: out[NV*HD + e*3H + 2H + j]
__device__ __forceinline__ long he_off(int e, int j) {
    return (long)NV * HD + (long)e * 3 * HD + 2 * HD + j;
}

// ---------------------------------------------------------------------------
// dtype detector: sample even-parity ushorts of atom_ftr (N(0,1) data).
// bf16 data -> ushort is a bf16 normal, exponent field in [100,150] ~always.
// fp32 data -> even ushorts are low mantissa bits, ~uniform, ~20% in range.
// flag = 1 (bf16) iff >= 128 of 256 samples in range.
// ---------------------------------------------------------------------------
__global__ void detect_dtype(const unsigned short* __restrict__ a, int* __restrict__ flag) {
    __shared__ int cnt[256];
    int t = threadIdx.x;
    unsigned short u = a[t * 16];          // max index 4080 -> 8KB, safe either way
    int e = (u >> 7) & 0xFF;
    cnt[t] = (e >= 100 && e <= 150) ? 1 : 0;
    __syncthreads();
    for (int s = 128; s > 0; s >>= 1) {
        if (t < s) cnt[t] += cnt[t + s];
        __syncthreads();
    }
    if (t == 0) *flag = (cnt[0] >= 128) ? 1 : 0;
}

// ---------------------------------------------------------------------------
// Extract one-hot index per column of m [NV, NE] row-major: out[e] = row of
// the single nonzero in column e. 16B vector loads; NE divisible by 8 and 4
// so vectors never cross rows.
// ---------------------------------------------------------------------------
__global__ void extract_idx_k(const void* __restrict__ m_, int* __restrict__ out,
                              const int* __restrict__ flag) {
    const uint4* m = (const uint4*)m_;
    long stride = (long)gridDim.x * blockDim.x;
    long i0 = (long)blockIdx.x * blockDim.x + threadIdx.x;
    if (*flag) {  // bf16: 8 elements per uint4
        const long total = (long)NV * NE / 8;
        for (long i = i0; i < total; i += stride) {
            uint4 u = m[i];
            if ((u.x | u.y | u.z | u.w) == 0u) continue;
            long base = i * 8;
            int v = (int)(base >> 13);         // NE = 2^13
            int e0 = (int)(base & (NE - 1));
            const unsigned short* h = (const unsigned short*)&u;
#pragma unroll
            for (int k = 0; k < 8; k++)
                if (h[k] != 0) out[e0 + k] = v;
        }
    } else {      // fp32: 4 elements per uint4
        const long total = (long)NV * NE / 4;
        for (long i = i0; i < total; i += stride) {
            uint4 u = m[i];
            if ((u.x | u.y | u.z | u.w) == 0u) continue;
            long base = i * 4;
            int v = (int)(base >> 13);
            int e0 = (int)(base & (NE - 1));
            const unsigned* w = (const unsigned*)&u;
#pragma unroll
            for (int k = 0; k < 4; k++)
                if (w[k] != 0u) out[e0 + k] = v;
        }
    }
}

// ---------------------------------------------------------------------------
// hv = tanh(leaky(atom @ vW1.T + vb1) @ vW2.T + vb2)   one block per row
// ---------------------------------------------------------------------------
template<typename T>
__device__ void vlin_impl(const T* atom, const T* W1, const T* b1,
                          const T* W2, const T* b2, float* hv) {
    __shared__ float a[AD];
    __shared__ float t1[HD];
    int r = blockIdx.x, j = threadIdx.x;
    if (j < AD) a[j] = ldf(atom, (long)r * AD + j);
    __syncthreads();
    float s = ldf(b1, j);
#pragma unroll 8
    for (int k = 0; k < AD; k++) s += a[k] * ldf(W1, (long)j * AD + k);
    t1[j] = leaky(s);
    __syncthreads();
    float s2 = ldf(b2, j);
#pragma unroll 8
    for (int k = 0; k < HD; k++) s2 += t1[k] * ldf(W2, (long)j * HD + k);
    hv[(long)r * HD + j] = tanhf(s2);
}

__global__ void v_linear_k(const void* atom, const void* W1, const void* b1,
                           const void* W2, const void* b2,
                           const int* __restrict__ flag, float* __restrict__ hv) {
    if (*flag) vlin_impl<bf16>((const bf16*)atom, (const bf16*)W1, (const bf16*)b1,
                               (const bf16*)W2, (const bf16*)b2, hv);
    else       vlin_impl<float>((const float*)atom, (const float*)W1, (const float*)b1,
                                (const float*)W2, (const float*)b2, hv);
}

// he = tanh(leaky(bond @ eW1.T + eb1) @ eW2.T + eb2), stored into out he-slot
template<typename T>
__device__ void elin_impl(const T* bond, const T* W1, const T* b1,
                          const T* W2, const T* b2, T* out) {
    __shared__ float a[BD];
    __shared__ float t1[HD];
    int r = blockIdx.x, j = threadIdx.x;
    if (j < BD) a[j] = ldf(bond, (long)r * BD + j);
    __syncthreads();
    float s = ldf(b1, j);
#pragma unroll 8
    for (int k = 0; k < BD; k++) s += a[k] * ldf(W1, (long)j * BD + k);
    t1[j] = leaky(s);
    __syncthreads();
    float s2 = ldf(b2, j);
#pragma unroll 8
    for (int k = 0; k < HD; k++) s2 += t1[k] * ldf(W2, (long)j * HD + k);
    stf(out, he_off(r, j), tanhf(s2));
}

__global__ void e_linear_k(const void* bond, const void* W1, const void* b1,
                           const void* W2, const void* b2,
                           const int* __restrict__ flag, void* out) {
    if (*flag) elin_impl<bf16>((const bf16*)bond, (const bf16*)W1, (const bf16*)b1,
                               (const bf16*)W2, (const bf16*)b2, (bf16*)out);
    else       elin_impl<float>((const float*)bond, (const float*)W1, (const float*)b1,
                                (const float*)W2, (const float*)b2, (float*)out);
}

// acc = hv
__global__ void copy_hv(const float4* __restrict__ src, float4* __restrict__ dst) {
    int i = blockIdx.x * blockDim.x + threadIdx.x;
    if (i < NV * HD / 4) dst[i] = src[i];
}

// per edge: acc[src[e]] += relu(he[e] + hv[dst[e]])
template<typename T>
__device__ void epass_impl(const T* out, const float* hv, const int* src,
                           const int* dst, float* acc) {
    int e = blockIdx.x, j = threadIdx.x;
    int s = clampv(src[e]), d = clampv(dst[e]);
    float v = ldf(out, he_off(e, j)) + hv[(long)d * HD + j];
    v = v > 0.f ? v : 0.f;
    atomicAdd(&acc[(long)s * HD + j], v);
}

__global__ void edge_pass_k(const void* out, const float* __restrict__ hv,
                            const int* __restrict__ src, const int* __restrict__ dst,
                            float* __restrict__ acc, const int* __restrict__ flag) {
    if (*flag) epass_impl<bf16>((const bf16*)out, hv, src, dst, acc);
    else       epass_impl<float>((const float*)out, hv, src, dst, acc);
}

// hv = leaky(acc @ W[l].T + b[l])
template<typename T>
__device__ void mlp_impl(const float* acc, const T* W, const T* b, float* hv, int l) {
    __shared__ float x[HD];
    int r = blockIdx.x, j = threadIdx.x;
    x[j] = acc[(long)r * HD + j];
    __syncthreads();
    const long wo = (long)l * HD * HD + (long)j * HD;
    float s = ldf(b, (long)l * HD + j);
#pragma unroll 8
    for (int k = 0; k < HD; k++) s += x[k] * ldf(W, wo + k);
    hv[(long)r * HD + j] = leaky(s);
}

__global__ void mlp_layer_k(const float* __restrict__ acc, const void* W, const void* b,
                            const int* __restrict__ flag, float* __restrict__ hv, int l) {
    if (*flag) mlp_impl<bf16>(acc, (const bf16*)W, (const bf16*)b, hv, l);
    else       mlp_impl<float>(acc, (const float*)W, (const float*)b, hv, l);
}

// out[0 : NV*HD] = hv
__global__ void out_hv_k(const float* __restrict__ hv, void* out,
                         const int* __restrict__ flag) {
    int i = blockIdx.x * blockDim.x + threadIdx.x;
    if (i >= NV * HD) return;
    if (*flag) stf((bf16*)out, i, hv[i]);
    else       stf((float*)out, i, hv[i]);
}

// out he_out gather sections: [hv[src[e]] | hv[dst[e]] | (he already in place)]
template<typename T>
__device__ void ohe_impl(const float* hv, const int* src, const int* dst, T* out) {
    int e = blockIdx.x, j = threadIdx.x;
    long o = (long)NV * HD + (long)e * 3 * HD;
    int s = clampv(src[e]), d = clampv(dst[e]);
    stf(out, o + j,      hv[(long)s * HD + j]);
    stf(out, o + HD + j, hv[(long)d * HD + j]);
}

__global__ void out_he_k(const float* __restrict__ hv, const int* __restrict__ src,
                         const int* __restrict__ dst, void* out,
                         const int* __restrict__ flag) {
    if (*flag) ohe_impl<bf16>(hv, src, dst, (bf16*)out);
    else       ohe_impl<float>(hv, src, dst, (float*)out);
}

extern "C" void kernel_launch(void* const* d_in, const int* in_sizes, int n_in,
                              void* d_out, int out_size, void* d_ws, size_t ws_size,
                              hipStream_t stream) {
    // Workspace layout (~4.3 MB total)
    char* ws = (char*)d_ws;
    int*   flag = (int*)ws;                        // 4 B (padded to 256)
    int*   src  = (int*)(ws + 256);                // NE ints
    int*   dst  = src + NE;                        // NE ints
    float* hv   = (float*)(ws + 256 + 2 * NE * 4); // NV*HD fp32 (2 MB)
    float* acc  = hv + (long)NV * HD;              // NV*HD fp32 (2 MB)

    // 0) detect element dtype (bf16 vs fp32) from atom_ftr bit patterns
    detect_dtype<<<1, 256, 0, stream>>>((const unsigned short*)d_in[0], flag);

    // 1) recover src/dst indices from the dense one-hot incidence matrices
    extract_idx_k<<<8192, 256, 0, stream>>>(d_in[2], src, flag);
    extract_idx_k<<<8192, 256, 0, stream>>>(d_in[3], dst, flag);

    // 2) node / edge input MLPs (he goes straight to its final out slot)
    v_linear_k<<<NV, HD, 0, stream>>>(d_in[0], d_in[4], d_in[5], d_in[6], d_in[7], flag, hv);
    e_linear_k<<<NE, HD, 0, stream>>>(d_in[1], d_in[8], d_in[9], d_in[10], d_in[11], flag, d_out);

    // 3) message-passing layers
    for (int l = 0; l < NL; l++) {
        copy_hv<<<(NV * HD / 4 + 255) / 256, 256, 0, stream>>>((const float4*)hv, (float4*)acc);
        edge_pass_k<<<NE, HD, 0, stream>>>(d_out, hv, src, dst, acc, flag);
        mlp_layer_k<<<NV, HD, 0, stream>>>(acc, d_in[12], d_in[13], flag, hv, l);
    }

    // 4) outputs
    out_hv_k<<<(NV * HD + 255) / 256, 256, 0, stream>>>(hv, d_out, flag);
    out_he_k<<<NE, HD, 0, stream>>>(hv, src, dst, d_out, flag);
}

// Round 3
// 504.396 us; speedup vs baseline: 1.1581x; 1.1581x over previous
//
#include <hip/hip_runtime.h>
#include <hip/hip_bf16.h>

#define NV 4096
#define NE 8192
#define AD 64      // ATOM_DIM
#define BD 32      // BOND_DIM_P1
#define HD 128     // H
#define NL 4       // N_LAYER

typedef __hip_bfloat16 bf16;
typedef unsigned short ushort_t;

__device__ __forceinline__ float leaky(float x) { return x > 0.f ? x : 0.01f * x; }
__device__ __forceinline__ int clampv(int x) { return min(max(x, 0), NV - 1); }
__device__ __forceinline__ float ldsel(const void* p, long i, int isbf) {
    return isbf ? __bfloat162float(((const bf16*)p)[i]) : ((const float*)p)[i];
}
__device__ __forceinline__ ushort_t f2us(float v) {
    bf16 h = __float2bfloat16(v);
    return *(ushort_t*)&h;
}

// ---- fp32 weight scratch layout (float offsets from wbase) ----
#define W_VW1T 0           // [64][128]   Wt[k][j] = W[j][k]
#define W_VW2T 8192        // [128][128]
#define W_EW1T 24576       // [32][128]
#define W_EW2T 28672       // [128][128]
#define W_MWT  45056       // [4][128][128]
#define W_VB1  110592
#define W_VB2  110720
#define W_EB1  110848
#define W_EB2  110976
#define W_MB   111104      // [4][128]
#define W_TOTAL 111616     // 446464 bytes

// out-buffer scratch (byte offsets; guaranteed out bytes >= out_size*2 = 7340032)
#define WB_OFF  2686976ULL   // weights: [2686976, 3133440) — dead after last mlp
#define HEF_OFF 3145728ULL   // he fp32:  [3145728, 7340032) — dead after he_pack
// out_hv writes [0, 1MB) bf16 (or [0,2MB) fp32): no overlap with scratch.
// out_he overwrites everything >= 1MB only AFTER scratch is dead.

// ---------------------------------------------------------------------------
// dtype detector (proven in round 2)
// ---------------------------------------------------------------------------
__global__ void detect_dtype(const ushort_t* __restrict__ a, int* __restrict__ flag) {
    __shared__ int cnt[256];
    int t = threadIdx.x;
    ushort_t u = a[t * 16];
    int e = (u >> 7) & 0xFF;
    cnt[t] = (e >= 100 && e <= 150) ? 1 : 0;
    __syncthreads();
    for (int s = 128; s > 0; s >>= 1) {
        if (t < s) cnt[t] += cnt[t + s];
        __syncthreads();
    }
    if (t == 0) *flag = (cnt[0] >= 128) ? 1 : 0;
}

// ---------------------------------------------------------------------------
// one-hot column index extraction (proven in round 2)
// ---------------------------------------------------------------------------
__global__ void extract_idx_k(const void* __restrict__ m_, int* __restrict__ out,
                              const int* __restrict__ flag) {
    const uint4* m = (const uint4*)m_;
    long stride = (long)gridDim.x * blockDim.x;
    long i0 = (long)blockIdx.x * blockDim.x + threadIdx.x;
    if (*flag) {
        const long total = (long)NV * NE / 8;
        for (long i = i0; i < total; i += stride) {
            uint4 u = m[i];
            if ((u.x | u.y | u.z | u.w) == 0u) continue;
            long base = i * 8;
            int v = (int)(base >> 13);
            int e0 = (int)(base & (NE - 1));
            const ushort_t* h = (const ushort_t*)&u;
#pragma unroll
            for (int k = 0; k < 8; k++)
                if (h[k] != 0) out[e0 + k] = v;
        }
    } else {
        const long total = (long)NV * NE / 4;
        for (long i = i0; i < total; i += stride) {
            uint4 u = m[i];
            if ((u.x | u.y | u.z | u.w) == 0u) continue;
            long base = i * 4;
            int v = (int)(base >> 13);
            int e0 = (int)(base & (NE - 1));
            const unsigned* w = (const unsigned*)&u;
#pragma unroll
            for (int k = 0; k < 4; k++)
                if (w[k] != 0u) out[e0 + k] = v;
        }
    }
}

// ---------------------------------------------------------------------------
// prep: transpose all weights to fp32 Wt[k][j] + fp32 biases into wbase
// ---------------------------------------------------------------------------
__global__ void prep_weights_k(const void* vW1, const void* vW2, const void* eW1,
                               const void* eW2, const void* mW,
                               const void* vb1, const void* vb2,
                               const void* eb1, const void* eb2, const void* mb,
                               const int* __restrict__ flag, float* __restrict__ wb) {
    int i = blockIdx.x * 256 + threadIdx.x;
    if (i >= W_TOTAL) return;
    int f = *flag;
    float v;
    if (i < W_VW2T)      { int t = i;          int k = t / 128, j = t % 128; v = ldsel(vW1, (long)j * AD + k, f); }
    else if (i < W_EW1T) { int t = i - W_VW2T; int k = t / 128, j = t % 128; v = ldsel(vW2, (long)j * HD + k, f); }
    else if (i < W_EW2T) { int t = i - W_EW1T; int k = t / 128, j = t % 128; v = ldsel(eW1, (long)j * BD + k, f); }
    else if (i < W_MWT)  { int t = i - W_EW2T; int k = t / 128, j = t % 128; v = ldsel(eW2, (long)j * HD + k, f); }
    else if (i < W_VB1)  { int t = i - W_MWT;  int l = t / 16384, r = t % 16384;
                           int k = r / 128, j = r % 128;
                           v = ldsel(mW, (long)l * 16384 + (long)j * HD + k, f); }
    else if (i < W_VB2)  v = ldsel(vb1, i - W_VB1, f);
    else if (i < W_EB1)  v = ldsel(vb2, i - W_VB2, f);
    else if (i < W_EB2)  v = ldsel(eb1, i - W_EB1, f);
    else if (i < W_MB)   v = ldsel(eb2, i - W_EB2, f);
    else                 v = ldsel(mb,  i - W_MB,  f);
    wb[i] = v;
}

// ---------------------------------------------------------------------------
// micro-GEMM: one thread computes C[row][j0..j0+3] over K.
// xrow: LDS, broadcast float4 reads. Wt: global fp32 [K][128], coalesced float4.
// ---------------------------------------------------------------------------
template<int K>
__device__ __forceinline__ float4 gemm_row(const float* __restrict__ xrow,
                                           const float* __restrict__ Wt, int jg) {
    float4 c = make_float4(0.f, 0.f, 0.f, 0.f);
    const float4* W4 = (const float4*)Wt;
#pragma unroll 8
    for (int k = 0; k < K; k += 4) {
        float4 xv = *(const float4*)(xrow + k);
        float4 w0 = W4[(k + 0) * 32 + jg];
        float4 w1 = W4[(k + 1) * 32 + jg];
        float4 w2 = W4[(k + 2) * 32 + jg];
        float4 w3 = W4[(k + 3) * 32 + jg];
        c.x = fmaf(xv.x, w0.x, fmaf(xv.y, w1.x, fmaf(xv.z, w2.x, fmaf(xv.w, w3.x, c.x))));
        c.y = fmaf(xv.x, w0.y, fmaf(xv.y, w1.y, fmaf(xv.z, w2.y, fmaf(xv.w, w3.y, c.y))));
        c.z = fmaf(xv.x, w0.z, fmaf(xv.y, w1.z, fmaf(xv.z, w2.z, fmaf(xv.w, w3.z, c.z))));
        c.w = fmaf(xv.x, w0.w, fmaf(xv.y, w1.w, fmaf(xv.z, w2.w, fmaf(xv.w, w3.w, c.w))));
    }
    return c;
}

// hv = tanh(leaky(atom @ vW1.T + b1) @ vW2.T + b2); also acc = hv
// 4 rows/block, 128 threads: jg = t&31 (j0=4jg), rg = t>>5 (row)
__global__ void v_linear_k(const void* atom, const float* __restrict__ wb,
                           const int* __restrict__ flag,
                           float* __restrict__ hv, float* __restrict__ acc) {
    __shared__ __align__(16) float xs[4 * AD];
    __shared__ __align__(16) float t1[4 * HD];
    int t = threadIdx.x, r0 = blockIdx.x * 4, f = *flag;
    for (int i = t; i < 4 * AD; i += 128) {
        int r = i >> 6, c = i & (AD - 1);
        xs[i] = ldsel(atom, (long)(r0 + r) * AD + c, f);
    }
    __syncthreads();
    int jg = t & 31, rg = t >> 5, j0 = jg * 4;
    float4 c1 = gemm_row<AD>(xs + rg * AD, wb + W_VW1T, jg);
    float4 b1 = *(const float4*)(wb + W_VB1 + j0);
    c1.x = leaky(c1.x + b1.x); c1.y = leaky(c1.y + b1.y);
    c1.z = leaky(c1.z + b1.z); c1.w = leaky(c1.w + b1.w);
    *(float4*)(t1 + rg * HD + j0) = c1;
    __syncthreads();
    float4 c2 = gemm_row<HD>(t1 + rg * HD, wb + W_VW2T, jg);
    float4 b2 = *(const float4*)(wb + W_VB2 + j0);
    c2.x = tanhf(c2.x + b2.x); c2.y = tanhf(c2.y + b2.y);
    c2.z = tanhf(c2.z + b2.z); c2.w = tanhf(c2.w + b2.w);
    long o = (long)(r0 + rg) * HD + j0;
    *(float4*)(hv + o) = c2;
    *(float4*)(acc + o) = c2;
}

// he = tanh(leaky(bond @ eW1.T + b1) @ eW2.T + b2) -> fp32 scratch
__global__ void e_linear_k(const void* bond, const float* __restrict__ wb,
                           const int* __restrict__ flag, float* __restrict__ hef) {
    __shared__ __align__(16) float xs[4 * BD];
    __shared__ __align__(16) float t1[4 * HD];
    int t = threadIdx.x, r0 = blockIdx.x * 4, f = *flag;
    if (t < 4 * BD) {
        int r = t >> 5, c = t & (BD - 1);
        xs[t] = ldsel(bond, (long)(r0 + r) * BD + c, f);
    }
    __syncthreads();
    int jg = t & 31, rg = t >> 5, j0 = jg * 4;
    float4 c1 = gemm_row<BD>(xs + rg * BD, wb + W_EW1T, jg);
    float4 b1 = *(const float4*)(wb + W_EB1 + j0);
    c1.x = leaky(c1.x + b1.x); c1.y = leaky(c1.y + b1.y);
    c1.z = leaky(c1.z + b1.z); c1.w = leaky(c1.w + b1.w);
    *(float4*)(t1 + rg * HD + j0) = c1;
    __syncthreads();
    float4 c2 = gemm_row<HD>(t1 + rg * HD, wb + W_EW2T, jg);
    float4 b2 = *(const float4*)(wb + W_EB2 + j0);
    c2.x = tanhf(c2.x + b2.x); c2.y = tanhf(c2.y + b2.y);
    c2.z = tanhf(c2.z + b2.z); c2.w = tanhf(c2.w + b2.w);
    *(float4*)(hef + (long)(r0 + rg) * HD + j0) = c2;
}

// per edge: acc[src[e]] += relu(he[e] + hv[dst[e]]); 2 edges per 256-thr block
__global__ void edge_pass_k(const float* __restrict__ hef, const float* __restrict__ hv,
                            const int* __restrict__ src, const int* __restrict__ dst,
                            float* __restrict__ acc) {
    int t = threadIdx.x;
    int e = blockIdx.x * 2 + (t >> 7), j = t & 127;
    int s = clampv(src[e]), d = clampv(dst[e]);
    float v = hef[(long)e * HD + j] + hv[(long)d * HD + j];
    v = v > 0.f ? v : 0.f;
    atomicAdd(acc + (long)s * HD + j, v);
}

// hv = leaky(acc @ W[l].T + b[l]); also acc = hv (init for next layer)
__global__ void mlp_k(const float* __restrict__ accin, const float* __restrict__ wb,
                      float* __restrict__ hv, float* __restrict__ accout, int l) {
    __shared__ __align__(16) float xs[4 * HD];
    int t = threadIdx.x, r0 = blockIdx.x * 4;
    for (int i = t; i < 4 * HD; i += 128) xs[i] = accin[(long)r0 * HD + i];
    __syncthreads();
    int jg = t & 31, rg = t >> 5, j0 = jg * 4;
    float4 c = gemm_row<HD>(xs + rg * HD, wb + W_MWT + l * 16384, jg);
    float4 b = *(const float4*)(wb + W_MB + l * HD + j0);
    c.x = leaky(c.x + b.x); c.y = leaky(c.y + b.y);
    c.z = leaky(c.z + b.z); c.w = leaky(c.w + b.w);
    long o = (long)(r0 + rg) * HD + j0;
    *(float4*)(hv + o) = c;
    *(float4*)(accout + o) = c;
}

// stage he fp32 -> bf16 into (dead) acc region
__global__ void he_pack_k(const float4* __restrict__ hef, ushort4* __restrict__ hb) {
    int i = blockIdx.x * blockDim.x + threadIdx.x;
    if (i >= NE * HD / 4) return;
    float4 v = hef[i];
    ushort4 u;
    u.x = f2us(v.x); u.y = f2us(v.y); u.z = f2us(v.z); u.w = f2us(v.w);
    hb[i] = u;
}

__global__ void out_hv_k(const float4* __restrict__ hv, void* out,
                         const int* __restrict__ flag) {
    int i = blockIdx.x * blockDim.x + threadIdx.x;
    if (i >= NV * HD / 4) return;
    float4 v = hv[i];
    if (*flag) {
        ushort4 u;
        u.x = f2us(v.x); u.y = f2us(v.y); u.z = f2us(v.z); u.w = f2us(v.w);
        ((ushort4*)out)[i] = u;
    } else {
        ((float4*)out)[i] = v;
    }
}

// out he sections: [hv[src[e]] | hv[dst[e]] | he]; 64 threads/edge, 2 cols each
__global__ void out_he_k(const float* __restrict__ hv, const ushort_t* __restrict__ hb,
                         const int* __restrict__ src, const int* __restrict__ dst,
                         void* out, const int* __restrict__ flag) {
    int e = blockIdx.x, t = threadIdx.x, j0 = t * 2;
    int s = clampv(src[e]), d = clampv(dst[e]);
    float2 a = *(const float2*)(hv + (long)s * HD + j0);
    float2 b = *(const float2*)(hv + (long)d * HD + j0);
    long o = (long)NV * HD + (long)e * 3 * HD;
    if (*flag) {
        ushort_t* ob = (ushort_t*)out;
        ushort2 ua; ua.x = f2us(a.x); ua.y = f2us(a.y);
        ushort2 ub; ub.x = f2us(b.x); ub.y = f2us(b.y);
        *(ushort2*)(ob + o + j0) = ua;
        *(ushort2*)(ob + o + HD + j0) = ub;
        *(unsigned*)(ob + o + 2 * HD + j0) = *(const unsigned*)(hb + (long)e * HD + j0);
    } else {
        float* of = (float*)out;
        *(float2*)(of + o + j0) = a;
        *(float2*)(of + o + HD + j0) = b;
        of[o + 2 * HD + j0]     = __bfloat162float(*(const bf16*)(hb + (long)e * HD + j0));
        of[o + 2 * HD + j0 + 1] = __bfloat162float(*(const bf16*)(hb + (long)e * HD + j0 + 1));
    }
}

extern "C" void kernel_launch(void* const* d_in, const int* in_sizes, int n_in,
                              void* d_out, int out_size, void* d_ws, size_t ws_size,
                              hipStream_t stream) {
    // ws: proven 4.26 MB layout from round 2
    char* ws = (char*)d_ws;
    int*   flag = (int*)ws;
    int*   src  = (int*)(ws + 256);
    int*   dst  = src + NE;
    float* hv   = (float*)(ws + 256 + 2 * NE * 4);
    float* acc  = hv + (long)NV * HD;

    // scratch carved from d_out (overwritten only by final output kernels)
    char* ob = (char*)d_out;
    float* wb  = (float*)(ob + WB_OFF);
    float* hef = (float*)(ob + HEF_OFF);
    ushort_t* hb = (ushort_t*)acc;   // he bf16 staging (acc dead after last mlp)

    detect_dtype<<<1, 256, 0, stream>>>((const ushort_t*)d_in[0], flag);
    prep_weights_k<<<(W_TOTAL + 255) / 256, 256, 0, stream>>>(
        d_in[4], d_in[6], d_in[8], d_in[10], d_in[12],
        d_in[5], d_in[7], d_in[9], d_in[11], d_in[13], flag, wb);
    extract_idx_k<<<8192, 256, 0, stream>>>(d_in[2], src, flag);
    extract_idx_k<<<8192, 256, 0, stream>>>(d_in[3], dst, flag);

    v_linear_k<<<NV / 4, 128, 0, stream>>>(d_in[0], wb, flag, hv, acc);
    e_linear_k<<<NE / 4, 128, 0, stream>>>(d_in[1], wb, flag, hef);

    for (int l = 0; l < NL; l++) {
        edge_pass_k<<<NE / 2, 256, 0, stream>>>(hef, hv, src, dst, acc);
        mlp_k<<<NV / 4, 128, 0, stream>>>(acc, wb, hv, acc, l);
    }

    he_pack_k<<<NE * HD / 4 / 256, 256, 0, stream>>>((const float4*)hef, (ushort4*)hb);
    out_hv_k<<<NV * HD / 4 / 256, 256, 0, stream>>>((const float4*)hv, d_out, flag);
    out_he_k<<<NE, 64, 0, stream>>>(hv, hb, src, dst, d_out, flag);
}

// Round 6
// 458.532 us; speedup vs baseline: 1.2740x; 1.1000x over previous
//
#include <hip/hip_runtime.h>
#include <hip/hip_bf16.h>

#define NV 4096
#define NE 8192
#define AD 64      // ATOM_DIM
#define BD 32      // BOND_DIM_P1
#define HD 128     // H
#define NL 4       // N_LAYER

// Everything is fp32 (proven: r2/r3 passed via runtime-detected flag=0 path;
// r3 absmax 2^-9 == bf16 rounding of tanh-range he staging, the only bf16 step).

__device__ __forceinline__ float leaky(float x) { return x > 0.f ? x : 0.01f * x; }
__device__ __forceinline__ int clampv(int x) { return min(max(x, 0), NV - 1); }

// ---- fp32 weight scratch layout (float offsets), mapping proven in r3 ----
#define W_VW1T 0           // [64][128]   Wt[k][j] = W[j][k]
#define W_VW2T 8192        // [128][128]
#define W_EW1T 24576       // [32][128]
#define W_EW2T 28672       // [128][128]
#define W_MWT  45056       // [4][128][128]
#define W_VB1  110592
#define W_VB2  110720
#define W_EB1  110848
#define W_EB2  110976
#define W_MB   111104      // [4][128]
#define W_TOTAL 111616

// ---- out layout (float offsets): [hv 524288][per-edge 384: src|dst|he] ----
#define OUT_HE 524288
#define ESTR   384

// ---------------------------------------------------------------------------
// prep: transpose all weights + copy biases to fp32 scratch (r3-proven map)
// ---------------------------------------------------------------------------
__global__ void prep_weights_k(const float* __restrict__ vW1, const float* __restrict__ vW2,
                               const float* __restrict__ eW1, const float* __restrict__ eW2,
                               const float* __restrict__ mW,
                               const float* __restrict__ vb1, const float* __restrict__ vb2,
                               const float* __restrict__ eb1, const float* __restrict__ eb2,
                               const float* __restrict__ mb, float* __restrict__ wb) {
    int i = blockIdx.x * 256 + threadIdx.x;
    if (i >= W_TOTAL) return;
    float v;
    if (i < W_VW2T)      { int t = i;          int k = t / 128, j = t % 128; v = vW1[(long)j * AD + k]; }
    else if (i < W_EW1T) { int t = i - W_VW2T; int k = t / 128, j = t % 128; v = vW2[(long)j * HD + k]; }
    else if (i < W_EW2T) { int t = i - W_EW1T; int k = t / 128, j = t % 128; v = eW1[(long)j * BD + k]; }
    else if (i < W_MWT)  { int t = i - W_EW2T; int k = t / 128, j = t % 128; v = eW2[(long)j * HD + k]; }
    else if (i < W_VB1)  { int t = i - W_MWT;  int l = t / 16384, r = t % 16384;
                           int k = r / 128, j = r % 128;
                           v = mW[(long)l * 16384 + (long)j * HD + k]; }
    else if (i < W_VB2)  v = vb1[i - W_VB1];
    else if (i < W_EB1)  v = vb2[i - W_VB2];
    else if (i < W_EB2)  v = eb1[i - W_EB1];
    else if (i < W_MB)   v = eb2[i - W_EB2];
    else                 v = mb[i - W_MB];
    wb[i] = v;
}

// ---------------------------------------------------------------------------
// fp32 one-hot extraction, both matrices in one kernel.
// blocks [0,4096): vew1 row blk -> srcv ; [4096,8192): vew2 row -> dstv.
// One block owns one row: 8192 fp32 = 2048 uint4; 256 thr x 8 iters.
// ---------------------------------------------------------------------------
__global__ void extract_both_k(const uint4* __restrict__ vew1, const uint4* __restrict__ vew2,
                               int* __restrict__ srcv, int* __restrict__ dstv) {
    int blk = blockIdx.x, t = threadIdx.x;
    const uint4* m = (blk < 4096) ? vew1 : vew2;
    int* out = (blk < 4096) ? srcv : dstv;
    long base = (long)(blk & 4095) * 2048;
#pragma unroll
    for (int k = 0; k < 8; k++) {
        long i = base + k * 256 + t;
        uint4 u = m[i];
        if ((u.x | u.y | u.z | u.w) == 0u) continue;
        long el = i * 4;                   // flat fp32 element index
        int v = (int)(el >> 13);           // row (NE = 2^13)
        int e0 = (int)(el & (NE - 1));     // col
        if (u.x) out[e0 + 0] = v;
        if (u.y) out[e0 + 1] = v;
        if (u.z) out[e0 + 2] = v;
        if (u.w) out[e0 + 3] = v;
    }
}

// ---------------------------------------------------------------------------
// micro-GEMM (r3-proven): thread computes row x cols [4jg, 4jg+4) over K
// ---------------------------------------------------------------------------
template<int K>
__device__ __forceinline__ float4 gemm_row(const float* __restrict__ xrow,
                                           const float* __restrict__ Wt, int jg) {
    float4 c = make_float4(0.f, 0.f, 0.f, 0.f);
    const float4* W4 = (const float4*)Wt;
#pragma unroll 8
    for (int k = 0; k < K; k += 4) {
        float4 xv = *(const float4*)(xrow + k);
        float4 w0 = W4[(k + 0) * 32 + jg];
        float4 w1 = W4[(k + 1) * 32 + jg];
        float4 w2 = W4[(k + 2) * 32 + jg];
        float4 w3 = W4[(k + 3) * 32 + jg];
        c.x = fmaf(xv.x, w0.x, fmaf(xv.y, w1.x, fmaf(xv.z, w2.x, fmaf(xv.w, w3.x, c.x))));
        c.y = fmaf(xv.x, w0.y, fmaf(xv.y, w1.y, fmaf(xv.z, w2.y, fmaf(xv.w, w3.y, c.y))));
        c.z = fmaf(xv.x, w0.z, fmaf(xv.y, w1.z, fmaf(xv.z, w2.z, fmaf(xv.w, w3.z, c.z))));
        c.w = fmaf(xv.x, w0.w, fmaf(xv.y, w1.w, fmaf(xv.z, w2.w, fmaf(xv.w, w3.w, c.w))));
    }
    return c;
}

// ---------------------------------------------------------------------------
// fused input MLPs (math r3-proven):
// blocks [0,1024): node rows -> hv (ws) + acc (ws)
// blocks [1024,3072): edge rows -> he straight into final out slot (fp32)
// ---------------------------------------------------------------------------
__global__ void vlin_elin_k(const float* __restrict__ atom, const float* __restrict__ bond,
                            const float* __restrict__ wb,
                            float* __restrict__ hv, float* __restrict__ acc,
                            float* __restrict__ outf) {
    __shared__ __align__(16) float xs[4 * AD];
    __shared__ __align__(16) float t1[4 * HD];
    int t = threadIdx.x, jg = t & 31, rg = t >> 5, j0 = jg * 4;
    if (blockIdx.x < NV / 4) {
        int r0 = blockIdx.x * 4;
        for (int i = t; i < 4 * AD; i += 128) xs[i] = atom[(long)r0 * AD + i];
        __syncthreads();
        float4 c1 = gemm_row<AD>(xs + rg * AD, wb + W_VW1T, jg);
        float4 b1 = *(const float4*)(wb + W_VB1 + j0);
        c1.x = leaky(c1.x + b1.x); c1.y = leaky(c1.y + b1.y);
        c1.z = leaky(c1.z + b1.z); c1.w = leaky(c1.w + b1.w);
        *(float4*)(t1 + rg * HD + j0) = c1;
        __syncthreads();
        float4 c2 = gemm_row<HD>(t1 + rg * HD, wb + W_VW2T, jg);
        float4 b2 = *(const float4*)(wb + W_VB2 + j0);
        c2.x = tanhf(c2.x + b2.x); c2.y = tanhf(c2.y + b2.y);
        c2.z = tanhf(c2.z + b2.z); c2.w = tanhf(c2.w + b2.w);
        long o = (long)(r0 + rg) * HD + j0;
        *(float4*)(hv + o) = c2;
        *(float4*)(acc + o) = c2;
    } else {
        int r0 = (blockIdx.x - NV / 4) * 4;
        for (int i = t; i < 4 * BD; i += 128) xs[i] = bond[(long)r0 * BD + i];
        __syncthreads();
        float4 c1 = gemm_row<BD>(xs + rg * BD, wb + W_EW1T, jg);
        float4 b1 = *(const float4*)(wb + W_EB1 + j0);
        c1.x = leaky(c1.x + b1.x); c1.y = leaky(c1.y + b1.y);
        c1.z = leaky(c1.z + b1.z); c1.w = leaky(c1.w + b1.w);
        *(float4*)(t1 + rg * HD + j0) = c1;
        __syncthreads();
        float4 c2 = gemm_row<HD>(t1 + rg * HD, wb + W_EW2T, jg);
        float4 b2 = *(const float4*)(wb + W_EB2 + j0);
        c2.x = tanhf(c2.x + b2.x); c2.y = tanhf(c2.y + b2.y);
        c2.z = tanhf(c2.z + b2.z); c2.w = tanhf(c2.w + b2.w);
        *(float4*)(outf + (long)OUT_HE + (long)(r0 + rg) * ESTR + 2 * HD + j0) = c2;
    }
}

// per edge: acc[src[e]] += relu(he[e] + hv[dst[e]]) — he read from out slot
__global__ void edge_pass_k(const float* __restrict__ outf, const float* __restrict__ hv,
                            const int* __restrict__ src, const int* __restrict__ dst,
                            float* __restrict__ acc) {
    int t = threadIdx.x;
    int e = blockIdx.x * 2 + (t >> 7), j = t & 127;
    int s = clampv(src[e]), d = clampv(dst[e]);
    float v = outf[(long)OUT_HE + (long)e * ESTR + 2 * HD + j] + hv[(long)d * HD + j];
    v = v > 0.f ? v : 0.f;
    atomicAdd(acc + (long)s * HD + j, v);
}

// hv = leaky(acc @ W[l].T + b[l]); acc = hv; on last layer also write out-hv
__global__ void mlp_k(const float* __restrict__ accin, const float* __restrict__ wb,
                      float* __restrict__ hv, float* __restrict__ accout, int l,
                      float* hv_out) {
    __shared__ __align__(16) float xs[4 * HD];
    int t = threadIdx.x, r0 = blockIdx.x * 4;
    for (int i = t; i < 4 * HD; i += 128) xs[i] = accin[(long)r0 * HD + i];
    __syncthreads();
    int jg = t & 31, rg = t >> 5, j0 = jg * 4;
    float4 c = gemm_row<HD>(xs + rg * HD, wb + W_MWT + l * 16384, jg);
    float4 b = *(const float4*)(wb + W_MB + l * HD + j0);
    c.x = leaky(c.x + b.x); c.y = leaky(c.y + b.y);
    c.z = leaky(c.z + b.z); c.w = leaky(c.w + b.w);
    long o = (long)(r0 + rg) * HD + j0;
    *(float4*)(hv + o) = c;
    *(float4*)(accout + o) = c;
    if (hv_out) *(float4*)(hv_out + o) = c;
}

// gather sections: out[e] = [hv[src[e]] | hv[dst[e]] | he(already in place)]
__global__ void out_he_k(const float* __restrict__ hv,
                         const int* __restrict__ src, const int* __restrict__ dst,
                         float* __restrict__ outf) {
    int e = blockIdx.x, t = threadIdx.x, j0 = t * 2;
    int s = clampv(src[e]), d = clampv(dst[e]);
    float2 a = *(const float2*)(hv + (long)s * HD + j0);
    float2 b = *(const float2*)(hv + (long)d * HD + j0);
    float* base = outf + (long)OUT_HE + (long)e * ESTR;
    *(float2*)(base + j0) = a;
    *(float2*)(base + HD + j0) = b;
}

extern "C" void kernel_launch(void* const* d_in, const int* in_sizes, int n_in,
                              void* d_out, int out_size, void* d_ws, size_t ws_size,
                              hipStream_t stream) {
    // ws layout (~4.8 MB; ws_size ~512 MiB per r3's poison-fill WRITE_SIZE)
    char* ws = (char*)d_ws;
    int*   srcv = (int*)ws;                         // NE
    int*   dstv = srcv + NE;                        // NE
    float* wb   = (float*)(ws + 2 * NE * 4);        // W_TOTAL floats
    float* hv   = wb + W_TOTAL;                     // NV*HD
    float* acc  = hv + (long)NV * HD;               // NV*HD
    float* outf = (float*)d_out;

    prep_weights_k<<<(W_TOTAL + 255) / 256, 256, 0, stream>>>(
        (const float*)d_in[4], (const float*)d_in[6], (const float*)d_in[8],
        (const float*)d_in[10], (const float*)d_in[12],
        (const float*)d_in[5], (const float*)d_in[7], (const float*)d_in[9],
        (const float*)d_in[11], (const float*)d_in[13], wb);
    extract_both_k<<<8192, 256, 0, stream>>>((const uint4*)d_in[2], (const uint4*)d_in[3],
                                             srcv, dstv);
    vlin_elin_k<<<3 * NV / 4, 128, 0, stream>>>((const float*)d_in[0], (const float*)d_in[1],
                                                wb, hv, acc, outf);

    for (int l = 0; l < NL; l++) {
        edge_pass_k<<<NE / 2, 256, 0, stream>>>(outf, hv, srcv, dstv, acc);
        mlp_k<<<NV / 4, 128, 0, stream>>>(acc, wb, hv, acc, l,
                                          (l == NL - 1) ? outf : nullptr);
    }

    out_he_k<<<NE, 64, 0, stream>>>(hv, srcv, dstv, outf);
}

// Round 7
// 457.574 us; speedup vs baseline: 1.2766x; 1.0021x over previous
//
#include <hip/hip_runtime.h>
#include <hip/hip_bf16.h>

#define NV 4096
#define NE 8192
#define AD 64      // ATOM_DIM
#define BD 32      // BOND_DIM_P1
#define HD 128     // H
#define NL 4       // N_LAYER

// Everything is fp32 (proven in r6: passed end-to-end fp32).

__device__ __forceinline__ float leaky(float x) { return x > 0.f ? x : 0.01f * x; }
__device__ __forceinline__ int clampv(int x) { return min(max(x, 0), NV - 1); }

// ---- fp32 weight scratch layout (float offsets), mapping proven in r3/r6 ----
#define W_VW1T 0           // [64][128]   Wt[k][j] = W[j][k]
#define W_VW2T 8192        // [128][128]
#define W_EW1T 24576       // [32][128]
#define W_EW2T 28672       // [128][128]
#define W_MWT  45056       // [4][128][128]
#define W_VB1  110592
#define W_VB2  110720
#define W_EB1  110848
#define W_EB2  110976
#define W_MB   111104      // [4][128]
#define W_TOTAL 111616

// ---- out layout (float offsets): [hv 524288][per-edge 384: src|dst|he] ----
#define OUT_HE 524288
#define ESTR   384

// ---------------------------------------------------------------------------
// prep: transpose all weights + copy biases to fp32 scratch (r6-proven)
// ---------------------------------------------------------------------------
__global__ void prep_weights_k(const float* __restrict__ vW1, const float* __restrict__ vW2,
                               const float* __restrict__ eW1, const float* __restrict__ eW2,
                               const float* __restrict__ mW,
                               const float* __restrict__ vb1, const float* __restrict__ vb2,
                               const float* __restrict__ eb1, const float* __restrict__ eb2,
                               const float* __restrict__ mb, float* __restrict__ wb) {
    int i = blockIdx.x * 256 + threadIdx.x;
    if (i >= W_TOTAL) return;
    float v;
    if (i < W_VW2T)      { int t = i;          int k = t / 128, j = t % 128; v = vW1[(long)j * AD + k]; }
    else if (i < W_EW1T) { int t = i - W_VW2T; int k = t / 128, j = t % 128; v = vW2[(long)j * HD + k]; }
    else if (i < W_EW2T) { int t = i - W_EW1T; int k = t / 128, j = t % 128; v = eW1[(long)j * BD + k]; }
    else if (i < W_MWT)  { int t = i - W_EW2T; int k = t / 128, j = t % 128; v = eW2[(long)j * HD + k]; }
    else if (i < W_VB1)  { int t = i - W_MWT;  int l = t / 16384, r = t % 16384;
                           int k = r / 128, j = r % 128;
                           v = mW[(long)l * 16384 + (long)j * HD + k]; }
    else if (i < W_VB2)  v = vb1[i - W_VB1];
    else if (i < W_EB1)  v = vb2[i - W_VB2];
    else if (i < W_EB2)  v = eb1[i - W_EB1];
    else if (i < W_MB)   v = eb2[i - W_EB2];
    else                 v = mb[i - W_MB];
    wb[i] = v;
}

// ---------------------------------------------------------------------------
// fp32 one-hot extraction with memory-level parallelism:
// all 8 uint4 (128 B/thread) loaded into independent registers BEFORE any
// test (r6 had VGPR_Count=8 -> one load in flight -> latency-bound 100 us).
// blocks [0,4096): vew1 row blk -> srcv ; [4096,8192): vew2 row -> dstv.
// ---------------------------------------------------------------------------
__global__ void extract_both_k(const uint4* __restrict__ vew1, const uint4* __restrict__ vew2,
                               int* __restrict__ srcv, int* __restrict__ dstv) {
    int blk = blockIdx.x, t = threadIdx.x;
    const uint4* m = (blk < 4096) ? vew1 : vew2;
    int* out = (blk < 4096) ? srcv : dstv;
    const uint4* p = m + (long)(blk & 4095) * 2048 + t;
    // 8 independent loads, stride 256 uint4 (4 KB)
    uint4 u0 = p[0];
    uint4 u1 = p[256];
    uint4 u2 = p[512];
    uint4 u3 = p[768];
    uint4 u4 = p[1024];
    uint4 u5 = p[1280];
    uint4 u6 = p[1536];
    uint4 u7 = p[1792];
    unsigned o0 = u0.x | u0.y | u0.z | u0.w;
    unsigned o1 = u1.x | u1.y | u1.z | u1.w;
    unsigned o2 = u2.x | u2.y | u2.z | u2.w;
    unsigned o3 = u3.x | u3.y | u3.z | u3.w;
    unsigned o4 = u4.x | u4.y | u4.z | u4.w;
    unsigned o5 = u5.x | u5.y | u5.z | u5.w;
    unsigned o6 = u6.x | u6.y | u6.z | u6.w;
    unsigned o7 = u7.x | u7.y | u7.z | u7.w;
    if ((o0 | o1 | o2 | o3 | o4 | o5 | o6 | o7) == 0u) return;
    // rare path (~1.6% of threads): inspect the 8 vectors
    int v = blk & 4095;
    uint4 us[8] = {u0, u1, u2, u3, u4, u5, u6, u7};
    unsigned os[8] = {o0, o1, o2, o3, o4, o5, o6, o7};
#pragma unroll
    for (int k = 0; k < 8; k++) {
        if (os[k] == 0u) continue;
        int e0 = (t + k * 256) * 4;        // column of us[k].x within the row
        if (us[k].x) out[e0 + 0] = v;
        if (us[k].y) out[e0 + 1] = v;
        if (us[k].z) out[e0 + 2] = v;
        if (us[k].w) out[e0 + 3] = v;
    }
}

// ---------------------------------------------------------------------------
// micro-GEMM (r3/r6-proven): thread computes row x cols [4jg, 4jg+4) over K
// ---------------------------------------------------------------------------
template<int K>
__device__ __forceinline__ float4 gemm_row(const float* __restrict__ xrow,
                                           const float* __restrict__ Wt, int jg) {
    float4 c = make_float4(0.f, 0.f, 0.f, 0.f);
    const float4* W4 = (const float4*)Wt;
#pragma unroll 8
    for (int k = 0; k < K; k += 4) {
        float4 xv = *(const float4*)(xrow + k);
        float4 w0 = W4[(k + 0) * 32 + jg];
        float4 w1 = W4[(k + 1) * 32 + jg];
        float4 w2 = W4[(k + 2) * 32 + jg];
        float4 w3 = W4[(k + 3) * 32 + jg];
        c.x = fmaf(xv.x, w0.x, fmaf(xv.y, w1.x, fmaf(xv.z, w2.x, fmaf(xv.w, w3.x, c.x))));
        c.y = fmaf(xv.x, w0.y, fmaf(xv.y, w1.y, fmaf(xv.z, w2.y, fmaf(xv.w, w3.y, c.y))));
        c.z = fmaf(xv.x, w0.z, fmaf(xv.y, w1.z, fmaf(xv.z, w2.z, fmaf(xv.w, w3.z, c.z))));
        c.w = fmaf(xv.x, w0.w, fmaf(xv.y, w1.w, fmaf(xv.z, w2.w, fmaf(xv.w, w3.w, c.w))));
    }
    return c;
}

// ---------------------------------------------------------------------------
// fused input MLPs (r6-proven):
// blocks [0,1024): node rows -> hv (ws) + acc (ws)
// blocks [1024,3072): edge rows -> he straight into final out slot (fp32)
// ---------------------------------------------------------------------------
__global__ void vlin_elin_k(const float* __restrict__ atom, const float* __restrict__ bond,
                            const float* __restrict__ wb,
                            float* __restrict__ hv, float* __restrict__ acc,
                            float* __restrict__ outf) {
    __shared__ __align__(16) float xs[4 * AD];
    __shared__ __align__(16) float t1[4 * HD];
    int t = threadIdx.x, jg = t & 31, rg = t >> 5, j0 = jg * 4;
    if (blockIdx.x < NV / 4) {
        int r0 = blockIdx.x * 4;
        for (int i = t; i < 4 * AD; i += 128) xs[i] = atom[(long)r0 * AD + i];
        __syncthreads();
        float4 c1 = gemm_row<AD>(xs + rg * AD, wb + W_VW1T, jg);
        float4 b1 = *(const float4*)(wb + W_VB1 + j0);
        c1.x = leaky(c1.x + b1.x); c1.y = leaky(c1.y + b1.y);
        c1.z = leaky(c1.z + b1.z); c1.w = leaky(c1.w + b1.w);
        *(float4*)(t1 + rg * HD + j0) = c1;
        __syncthreads();
        float4 c2 = gemm_row<HD>(t1 + rg * HD, wb + W_VW2T, jg);
        float4 b2 = *(const float4*)(wb + W_VB2 + j0);
        c2.x = tanhf(c2.x + b2.x); c2.y = tanhf(c2.y + b2.y);
        c2.z = tanhf(c2.z + b2.z); c2.w = tanhf(c2.w + b2.w);
        long o = (long)(r0 + rg) * HD + j0;
        *(float4*)(hv + o) = c2;
        *(float4*)(acc + o) = c2;
    } else {
        int r0 = (blockIdx.x - NV / 4) * 4;
        for (int i = t; i < 4 * BD; i += 128) xs[i] = bond[(long)r0 * BD + i];
        __syncthreads();
        float4 c1 = gemm_row<BD>(xs + rg * BD, wb + W_EW1T, jg);
        float4 b1 = *(const float4*)(wb + W_EB1 + j0);
        c1.x = leaky(c1.x + b1.x); c1.y = leaky(c1.y + b1.y);
        c1.z = leaky(c1.z + b1.z); c1.w = leaky(c1.w + b1.w);
        *(float4*)(t1 + rg * HD + j0) = c1;
        __syncthreads();
        float4 c2 = gemm_row<HD>(t1 + rg * HD, wb + W_EW2T, jg);
        float4 b2 = *(const float4*)(wb + W_EB2 + j0);
        c2.x = tanhf(c2.x + b2.x); c2.y = tanhf(c2.y + b2.y);
        c2.z = tanhf(c2.z + b2.z); c2.w = tanhf(c2.w + b2.w);
        *(float4*)(outf + (long)OUT_HE + (long)(r0 + rg) * ESTR + 2 * HD + j0) = c2;
    }
}

// per edge: acc[src[e]] += relu(he[e] + hv[dst[e]]) — r6-proven
__global__ void edge_pass_k(const float* __restrict__ outf, const float* __restrict__ hv,
                            const int* __restrict__ src, const int* __restrict__ dst,
                            float* __restrict__ acc) {
    int t = threadIdx.x;
    int e = blockIdx.x * 2 + (t >> 7), j = t & 127;
    int s = clampv(src[e]), d = clampv(dst[e]);
    float v = outf[(long)OUT_HE + (long)e * ESTR + 2 * HD + j] + hv[(long)d * HD + j];
    v = v > 0.f ? v : 0.f;
    atomicAdd(acc + (long)s * HD + j, v);
}

// hv = leaky(acc @ W[l].T + b[l]); acc = hv; on last layer also write out-hv
__global__ void mlp_k(const float* __restrict__ accin, const float* __restrict__ wb,
                      float* __restrict__ hv, float* __restrict__ accout, int l,
                      float* hv_out) {
    __shared__ __align__(16) float xs[4 * HD];
    int t = threadIdx.x, r0 = blockIdx.x * 4;
    for (int i = t; i < 4 * HD; i += 128) xs[i] = accin[(long)r0 * HD + i];
    __syncthreads();
    int jg = t & 31, rg = t >> 5, j0 = jg * 4;
    float4 c = gemm_row<HD>(xs + rg * HD, wb + W_MWT + l * 16384, jg);
    float4 b = *(const float4*)(wb + W_MB + l * HD + j0);
    c.x = leaky(c.x + b.x); c.y = leaky(c.y + b.y);
    c.z = leaky(c.z + b.z); c.w = leaky(c.w + b.w);
    long o = (long)(r0 + rg) * HD + j0;
    *(float4*)(hv + o) = c;
    *(float4*)(accout + o) = c;
    if (hv_out) *(float4*)(hv_out + o) = c;
}

// gather sections: out[e] = [hv[src[e]] | hv[dst[e]] | he(already in place)]
__global__ void out_he_k(const float* __restrict__ hv,
                         const int* __restrict__ src, const int* __restrict__ dst,
                         float* __restrict__ outf) {
    int e = blockIdx.x, t = threadIdx.x, j0 = t * 2;
    int s = clampv(src[e]), d = clampv(dst[e]);
    float2 a = *(const float2*)(hv + (long)s * HD + j0);
    float2 b = *(const float2*)(hv + (long)d * HD + j0);
    float* base = outf + (long)OUT_HE + (long)e * ESTR;
    *(float2*)(base + j0) = a;
    *(float2*)(base + HD + j0) = b;
}

extern "C" void kernel_launch(void* const* d_in, const int* in_sizes, int n_in,
                              void* d_out, int out_size, void* d_ws, size_t ws_size,
                              hipStream_t stream) {
    char* ws = (char*)d_ws;
    int*   srcv = (int*)ws;                         // NE
    int*   dstv = srcv + NE;                        // NE
    float* wb   = (float*)(ws + 2 * NE * 4);        // W_TOTAL floats
    float* hv   = wb + W_TOTAL;                     // NV*HD
    float* acc  = hv + (long)NV * HD;               // NV*HD
    float* outf = (float*)d_out;

    prep_weights_k<<<(W_TOTAL + 255) / 256, 256, 0, stream>>>(
        (const float*)d_in[4], (const float*)d_in[6], (const float*)d_in[8],
        (const float*)d_in[10], (const float*)d_in[12],
        (const float*)d_in[5], (const float*)d_in[7], (const float*)d_in[9],
        (const float*)d_in[11], (const float*)d_in[13], wb);
    extract_both_k<<<8192, 256, 0, stream>>>((const uint4*)d_in[2], (const uint4*)d_in[3],
                                             srcv, dstv);
    vlin_elin_k<<<3 * NV / 4, 128, 0, stream>>>((const float*)d_in[0], (const float*)d_in[1],
                                                wb, hv, acc, outf);

    for (int l = 0; l < NL; l++) {
        edge_pass_k<<<NE / 2, 256, 0, stream>>>(outf, hv, srcv, dstv, acc);
        mlp_k<<<NV / 4, 128, 0, stream>>>(acc, wb, hv, acc, l,
                                          (l == NL - 1) ? outf : nullptr);
    }

    out_he_k<<<NE, 64, 0, stream>>>(hv, srcv, dstv, outf);
}

// Round 8
// 433.283 us; speedup vs baseline: 1.3482x; 1.0561x over previous
//
#include <hip/hip_runtime.h>
#include <hip/hip_bf16.h>

#define NV 4096
#define NE 8192
#define AD 64      // ATOM_DIM
#define BD 32      // BOND_DIM_P1
#define HD 128     // H
#define NL 4       // N_LAYER

// Everything is fp32 (proven r6/r7).

__device__ __forceinline__ float leaky(float x) { return x > 0.f ? x : 0.01f * x; }
__device__ __forceinline__ int clampv(int x) { return min(max(x, 0), NV - 1); }

// ---- fp32 weight scratch layout (float offsets), proven r3/r6/r7 ----
#define W_VW1T 0           // [64][128]   Wt[k][j] = W[j][k]
#define W_VW2T 8192        // [128][128]
#define W_EW1T 24576       // [32][128]
#define W_EW2T 28672       // [128][128]
#define W_MWT  45056       // [4][128][128]
#define W_VB1  110592
#define W_VB2  110720
#define W_EB1  110848
#define W_EB2  110976
#define W_MB   111104      // [4][128]
#define W_TOTAL 111616     // = 436 * 256 exactly

// ---- out layout (float offsets): [hv 524288][per-edge 384: src|dst|he] ----
#define OUT_HE 524288
#define ESTR   384

// ---------------------------------------------------------------------------
// Fused extract + weight-prep.
// blocks [0,1024):    vew1 rows 4b..4b+3 -> srcv
// blocks [1024,2048): vew2 rows 4b..4b+3 -> dstv
// blocks [2048,2484): weight transpose (r6-proven mapping), 256 elems/block
//
// Extract: per block 4 rows = 8192 uint4; per thread 32 uint4 in 2 batches of
// 16 independent loads (r7 showed 4-5 in flight doesn't move the needle ->
// test 16-deep MLP + 4x fatter blocks to separate dispatch-granularity from
// fabric-BW ceiling). Each load instruction reads 4 KB contiguous per wavepair.
// ---------------------------------------------------------------------------
__global__ __launch_bounds__(256, 3)
void extract_prep_k(const uint4* __restrict__ vew1, const uint4* __restrict__ vew2,
                    int* __restrict__ srcv, int* __restrict__ dstv,
                    const float* __restrict__ vW1, const float* __restrict__ vW2,
                    const float* __restrict__ eW1, const float* __restrict__ eW2,
                    const float* __restrict__ mW,
                    const float* __restrict__ vb1, const float* __restrict__ vb2,
                    const float* __restrict__ eb1, const float* __restrict__ eb2,
                    const float* __restrict__ mb, float* __restrict__ wb) {
    int blk = blockIdx.x, t = threadIdx.x;
    if (blk < 2048) {
        const uint4* m = (blk < 1024) ? vew1 : vew2;
        int* out = (blk < 1024) ? srcv : dstv;
        int r0 = (blk & 1023) * 4;                    // first of 4 rows
        const uint4* p = m + (long)r0 * 2048;         // 8192 uint4 chunk
#pragma unroll
        for (int b = 0; b < 2; b++) {
            uint4 u[16];
            unsigned o[16];
            int base = b * 4096 + t;                  // uint4 index in chunk
#pragma unroll
            for (int k = 0; k < 16; k++) u[k] = p[base + k * 256];
#pragma unroll
            for (int k = 0; k < 16; k++) o[k] = u[k].x | u[k].y | u[k].z | u[k].w;
            unsigned any = 0;
#pragma unroll
            for (int k = 0; k < 16; k++) any |= o[k];
            if (any == 0u) continue;
            // rare path: ~8 nonzeros per block spread over 512 thread-batches
#pragma unroll
            for (int k = 0; k < 16; k++) {
                if (o[k] == 0u) continue;
                int i = base + k * 256;               // uint4 index in chunk
                int row = r0 + (i >> 11);             // 2048 uint4 per row
                int col = (i << 2) & (NE - 1);        // element col in row
                if (u[k].x) out[col + 0] = row;
                if (u[k].y) out[col + 1] = row;
                if (u[k].z) out[col + 2] = row;
                if (u[k].w) out[col + 3] = row;
            }
        }
    } else {
        int i = (blk - 2048) * 256 + t;
        if (i >= W_TOTAL) return;
        float v;
        if (i < W_VW2T)      { int q = i;          int k = q / 128, j = q % 128; v = vW1[(long)j * AD + k]; }
        else if (i < W_EW1T) { int q = i - W_VW2T; int k = q / 128, j = q % 128; v = vW2[(long)j * HD + k]; }
        else if (i < W_EW2T) { int q = i - W_EW1T; int k = q / 128, j = q % 128; v = eW1[(long)j * BD + k]; }
        else if (i < W_MWT)  { int q = i - W_EW2T; int k = q / 128, j = q % 128; v = eW2[(long)j * HD + k]; }
        else if (i < W_VB1)  { int q = i - W_MWT;  int l = q / 16384, r = q % 16384;
                               int k = r / 128, j = r % 128;
                               v = mW[(long)l * 16384 + (long)j * HD + k]; }
        else if (i < W_VB2)  v = vb1[i - W_VB1];
        else if (i < W_EB1)  v = vb2[i - W_VB2];
        else if (i < W_EB2)  v = eb1[i - W_EB1];
        else if (i < W_MB)   v = eb2[i - W_EB2];
        else                 v = mb[i - W_MB];
        wb[i] = v;
    }
}

// ---------------------------------------------------------------------------
// micro-GEMM (proven): thread computes row x cols [4jg, 4jg+4) over K
// ---------------------------------------------------------------------------
template<int K>
__device__ __forceinline__ float4 gemm_row(const float* __restrict__ xrow,
                                           const float* __restrict__ Wt, int jg) {
    float4 c = make_float4(0.f, 0.f, 0.f, 0.f);
    const float4* W4 = (const float4*)Wt;
#pragma unroll 8
    for (int k = 0; k < K; k += 4) {
        float4 xv = *(const float4*)(xrow + k);
        float4 w0 = W4[(k + 0) * 32 + jg];
        float4 w1 = W4[(k + 1) * 32 + jg];
        float4 w2 = W4[(k + 2) * 32 + jg];
        float4 w3 = W4[(k + 3) * 32 + jg];
        c.x = fmaf(xv.x, w0.x, fmaf(xv.y, w1.x, fmaf(xv.z, w2.x, fmaf(xv.w, w3.x, c.x))));
        c.y = fmaf(xv.x, w0.y, fmaf(xv.y, w1.y, fmaf(xv.z, w2.y, fmaf(xv.w, w3.y, c.y))));
        c.z = fmaf(xv.x, w0.z, fmaf(xv.y, w1.z, fmaf(xv.z, w2.z, fmaf(xv.w, w3.z, c.z))));
        c.w = fmaf(xv.x, w0.w, fmaf(xv.y, w1.w, fmaf(xv.z, w2.w, fmaf(xv.w, w3.w, c.w))));
    }
    return c;
}

// ---------------------------------------------------------------------------
// fused input MLPs (r6/r7-proven)
// ---------------------------------------------------------------------------
__global__ void vlin_elin_k(const float* __restrict__ atom, const float* __restrict__ bond,
                            const float* __restrict__ wb,
                            float* __restrict__ hv, float* __restrict__ acc,
                            float* __restrict__ outf) {
    __shared__ __align__(16) float xs[4 * AD];
    __shared__ __align__(16) float t1[4 * HD];
    int t = threadIdx.x, jg = t & 31, rg = t >> 5, j0 = jg * 4;
    if (blockIdx.x < NV / 4) {
        int r0 = blockIdx.x * 4;
        for (int i = t; i < 4 * AD; i += 128) xs[i] = atom[(long)r0 * AD + i];
        __syncthreads();
        float4 c1 = gemm_row<AD>(xs + rg * AD, wb + W_VW1T, jg);
        float4 b1 = *(const float4*)(wb + W_VB1 + j0);
        c1.x = leaky(c1.x + b1.x); c1.y = leaky(c1.y + b1.y);
        c1.z = leaky(c1.z + b1.z); c1.w = leaky(c1.w + b1.w);
        *(float4*)(t1 + rg * HD + j0) = c1;
        __syncthreads();
        float4 c2 = gemm_row<HD>(t1 + rg * HD, wb + W_VW2T, jg);
        float4 b2 = *(const float4*)(wb + W_VB2 + j0);
        c2.x = tanhf(c2.x + b2.x); c2.y = tanhf(c2.y + b2.y);
        c2.z = tanhf(c2.z + b2.z); c2.w = tanhf(c2.w + b2.w);
        long o = (long)(r0 + rg) * HD + j0;
        *(float4*)(hv + o) = c2;
        *(float4*)(acc + o) = c2;
    } else {
        int r0 = (blockIdx.x - NV / 4) * 4;
        for (int i = t; i < 4 * BD; i += 128) xs[i] = bond[(long)r0 * BD + i];
        __syncthreads();
        float4 c1 = gemm_row<BD>(xs + rg * BD, wb + W_EW1T, jg);
        float4 b1 = *(const float4*)(wb + W_EB1 + j0);
        c1.x = leaky(c1.x + b1.x); c1.y = leaky(c1.y + b1.y);
        c1.z = leaky(c1.z + b1.z); c1.w = leaky(c1.w + b1.w);
        *(float4*)(t1 + rg * HD + j0) = c1;
        __syncthreads();
        float4 c2 = gemm_row<HD>(t1 + rg * HD, wb + W_EW2T, jg);
        float4 b2 = *(const float4*)(wb + W_EB2 + j0);
        c2.x = tanhf(c2.x + b2.x); c2.y = tanhf(c2.y + b2.y);
        c2.z = tanhf(c2.z + b2.z); c2.w = tanhf(c2.w + b2.w);
        *(float4*)(outf + (long)OUT_HE + (long)(r0 + rg) * ESTR + 2 * HD + j0) = c2;
    }
}

// per edge: acc[src[e]] += relu(he[e] + hv[dst[e]]) — r6/r7-proven
__global__ void edge_pass_k(const float* __restrict__ outf, const float* __restrict__ hv,
                            const int* __restrict__ src, const int* __restrict__ dst,
                            float* __restrict__ acc) {
    int t = threadIdx.x;
    int e = blockIdx.x * 2 + (t >> 7), j = t & 127;
    int s = clampv(src[e]), d = clampv(dst[e]);
    float v = outf[(long)OUT_HE + (long)e * ESTR + 2 * HD + j] + hv[(long)d * HD + j];
    v = v > 0.f ? v : 0.f;
    atomicAdd(acc + (long)s * HD + j, v);
}

// hv = leaky(acc @ W[l].T + b[l]); acc = hv; on last layer also write out-hv
__global__ void mlp_k(const float* __restrict__ accin, const float* __restrict__ wb,
                      float* __restrict__ hv, float* __restrict__ accout, int l,
                      float* hv_out) {
    __shared__ __align__(16) float xs[4 * HD];
    int t = threadIdx.x, r0 = blockIdx.x * 4;
    for (int i = t; i < 4 * HD; i += 128) xs[i] = accin[(long)r0 * HD + i];
    __syncthreads();
    int jg = t & 31, rg = t >> 5, j0 = jg * 4;
    float4 c = gemm_row<HD>(xs + rg * HD, wb + W_MWT + l * 16384, jg);
    float4 b = *(const float4*)(wb + W_MB + l * HD + j0);
    c.x = leaky(c.x + b.x); c.y = leaky(c.y + b.y);
    c.z = leaky(c.z + b.z); c.w = leaky(c.w + b.w);
    long o = (long)(r0 + rg) * HD + j0;
    *(float4*)(hv + o) = c;
    *(float4*)(accout + o) = c;
    if (hv_out) *(float4*)(hv_out + o) = c;
}

// gather sections: out[e] = [hv[src[e]] | hv[dst[e]] | he(already in place)]
__global__ void out_he_k(const float* __restrict__ hv,
                         const int* __restrict__ src, const int* __restrict__ dst,
                         float* __restrict__ outf) {
    int e = blockIdx.x, t = threadIdx.x, j0 = t * 2;
    int s = clampv(src[e]), d = clampv(dst[e]);
    float2 a = *(const float2*)(hv + (long)s * HD + j0);
    float2 b = *(const float2*)(hv + (long)d * HD + j0);
    float* base = outf + (long)OUT_HE + (long)e * ESTR;
    *(float2*)(base + j0) = a;
    *(float2*)(base + HD + j0) = b;
}

extern "C" void kernel_launch(void* const* d_in, const int* in_sizes, int n_in,
                              void* d_out, int out_size, void* d_ws, size_t ws_size,
                              hipStream_t stream) {
    char* ws = (char*)d_ws;
    int*   srcv = (int*)ws;                         // NE
    int*   dstv = srcv + NE;                        // NE
    float* wb   = (float*)(ws + 2 * NE * 4);        // W_TOTAL floats
    float* hv   = wb + W_TOTAL;                     // NV*HD
    float* acc  = hv + (long)NV * HD;               // NV*HD
    float* outf = (float*)d_out;

    extract_prep_k<<<2048 + (W_TOTAL + 255) / 256, 256, 0, stream>>>(
        (const uint4*)d_in[2], (const uint4*)d_in[3], srcv, dstv,
        (const float*)d_in[4], (const float*)d_in[6], (const float*)d_in[8],
        (const float*)d_in[10], (const float*)d_in[12],
        (const float*)d_in[5], (const float*)d_in[7], (const float*)d_in[9],
        (const float*)d_in[11], (const float*)d_in[13], wb);
    vlin_elin_k<<<3 * NV / 4, 128, 0, stream>>>((const float*)d_in[0], (const float*)d_in[1],
                                                wb, hv, acc, outf);

    for (int l = 0; l < NL; l++) {
        edge_pass_k<<<NE / 2, 256, 0, stream>>>(outf, hv, srcv, dstv, acc);
        mlp_k<<<NV / 4, 128, 0, stream>>>(acc, wb, hv, acc, l,
                                          (l == NL - 1) ? outf : nullptr);
    }

    out_he_k<<<NE, 64, 0, stream>>>(hv, srcv, dstv, outf);
}